// Round 8
// baseline (1692.582 us; speedup 1.0000x reference)
//
#include <hip/hip_runtime.h>
#include <math.h>

#define KK 10
#define NN 96
#define TT 40

#define HZf 10.0f
#define R0f 0.5f
#define R1f 4.0f
#define RSTEPf ((4.0f - 0.5f) / 6.0f)
#define TWO_PIf 6.2831853071795864769f
#define TSTEPf (6.2831853071795864769f / 6.0f)

typedef unsigned short u16;
typedef unsigned int u32;
typedef unsigned long long u64;

__device__ __forceinline__ u16 f2bf(float f) {
    union { float f; unsigned u; } v; v.f = f;
    unsigned r = v.u + 0x7fffu + ((v.u >> 16) & 1u);
    return (u16)(r >> 16);
}
__device__ __forceinline__ float bflo(u32 u) {
    union { unsigned u; float f; } v; v.u = u << 16; return v.f;
}
__device__ __forceinline__ float bfhi(u32 u) {
    union { unsigned u; float f; } v; v.u = u & 0xffff0000u; return v.f;
}
__device__ __forceinline__ float bf2f(u16 h) {
    union { unsigned u; float f; } v; v.u = ((unsigned)h) << 16; return v.f;
}
__device__ __forceinline__ float sigmoidf_(float x) { return 1.0f / (1.0f + expf(-x)); }

// ---------------- conv1: (4,160,160) -> relu -> (16,80,80), s2 p2 ----------------
__global__ void conv1_k(const float* __restrict__ img, const float* __restrict__ w,
                        const float* __restrict__ b, float* __restrict__ out) {
    int idx = blockIdx.x * blockDim.x + threadIdx.x;
    if (idx >= 16 * 80 * 80) return;
    int x = idx % 80, y = (idx / 80) % 80, o = idx / 6400;
    float acc = b[o];
    for (int c = 0; c < 4; c++)
        for (int ky = 0; ky < 5; ky++) {
            int iy = y * 2 + ky - 2;
            if (iy < 0 || iy >= 160) continue;
            for (int kx = 0; kx < 5; kx++) {
                int ix = x * 2 + kx - 2;
                if (ix < 0 || ix >= 160) continue;
                acc += img[(c * 160 + iy) * 160 + ix] * w[((o * 4 + c) * 5 + ky) * 5 + kx];
            }
        }
    out[idx] = fmaxf(acc, 0.0f);
}

// ---------------- conv2: (16,80,80) -> relu -> (32,80,80), s1 p2 ----------------
__global__ void conv2_k(const float* __restrict__ in, const float* __restrict__ w,
                        const float* __restrict__ b, float* __restrict__ out) {
    int idx = blockIdx.x * blockDim.x + threadIdx.x;
    if (idx >= 32 * 80 * 80) return;
    int x = idx % 80, y = (idx / 80) % 80, o = idx / 6400;
    float acc = b[o];
    for (int c = 0; c < 16; c++)
        for (int ky = 0; ky < 5; ky++) {
            int iy = y + ky - 2;
            if (iy < 0 || iy >= 80) continue;
            for (int kx = 0; kx < 5; kx++) {
                int ix = x + kx - 2;
                if (ix < 0 || ix >= 80) continue;
                acc += in[(c * 80 + iy) * 80 + ix] * w[((o * 16 + c) * 5 + ky) * 5 + kx];
            }
        }
    out[idx] = fmaxf(acc, 0.0f);
}

// ---------------- weight prep: bf16 pair-packed planes ----------------
__global__ void prep_w3(const float* __restrict__ scf, const float* __restrict__ wih,
                        const float* __restrict__ whh, const float* __restrict__ bih,
                        const float* __restrict__ bhh, const float* __restrict__ scfb,
                        u32* __restrict__ wscf_p, u32* __restrict__ Wr_p,
                        u32* __restrict__ Wz_p, u32* __restrict__ Win_p,
                        u32* __restrict__ Whn_p, float* __restrict__ bias5) {
    int idx = blockIdx.x * blockDim.x + threadIdx.x;
    if (idx < 41472) {
        int o = idx % 48, dp = (idx / 48) % 24, b = idx / 1152;
        float v0 = scf[o * 1728 + b * 48 + 2 * dp];
        float v1 = scf[o * 1728 + b * 48 + 2 * dp + 1];
        wscf_p[idx] = (u32)f2bf(v0) | ((u32)f2bf(v1) << 16);
    } else if (idx < 44928) {
        int j = idx - 41472, od = j % 48, dp = j / 48;
        int kk0 = 2 * dp, kk1 = 2 * dp + 1;
        float v0 = kk0 < 96 ? wih[od * 96 + kk0] : whh[od * 48 + kk0 - 96];
        float v1 = kk1 < 96 ? wih[od * 96 + kk1] : whh[od * 48 + kk1 - 96];
        Wr_p[j] = (u32)f2bf(v0) | ((u32)f2bf(v1) << 16);
    } else if (idx < 48384) {
        int j = idx - 44928, od = j % 48, dp = j / 48;
        int row = 48 + od, kk0 = 2 * dp, kk1 = 2 * dp + 1;
        float v0 = kk0 < 96 ? wih[row * 96 + kk0] : whh[row * 48 + kk0 - 96];
        float v1 = kk1 < 96 ? wih[row * 96 + kk1] : whh[row * 48 + kk1 - 96];
        Wz_p[j] = (u32)f2bf(v0) | ((u32)f2bf(v1) << 16);
    } else if (idx < 50688) {
        int j = idx - 48384, od = j % 48, dp = j / 48;
        int row = 96 + od;
        Win_p[j] = (u32)f2bf(wih[row * 96 + 2 * dp]) | ((u32)f2bf(wih[row * 96 + 2 * dp + 1]) << 16);
    } else if (idx < 51840) {
        int j = idx - 50688, od = j % 48, dp = j / 48;
        int row = 96 + od;
        Whn_p[j] = (u32)f2bf(whh[row * 48 + 2 * dp]) | ((u32)f2bf(whh[row * 48 + 2 * dp + 1]) << 16);
    } else if (idx < 52080) {
        int j = idx - 51840, od = j % 48, q = j / 48;
        float v;
        if (q == 0) v = bih[od] + bhh[od];
        else if (q == 1) v = bih[48 + od] + bhh[48 + od];
        else if (q == 2) v = bih[96 + od];
        else if (q == 3) v = bhh[96 + od];
        else v = scfb[od];
        bias5[j] = v;
    }
}

// ---------------- lhalf (bf16) ----------------
__global__ void lhalf_k(const float* __restrict__ yp, const float* __restrict__ cur,
                        const float* __restrict__ fmap, const float* __restrict__ vw,
                        const float* __restrict__ vb, u16* __restrict__ lhalf_bf) {
    int item = blockIdx.x;  // t*960 + k*96 + n
    int n = item % NN, k = (item / NN) % KK, t = item / (KK * NN);
    int lane = threadIdx.x;
    float lx = yp[((k * TT + t) * NN + n) * 2 + 0];
    float ly = yp[((k * TT + t) * NN + n) * 2 + 1];
    float px, py;
    if (t == 0) { px = cur[n * 2]; py = cur[n * 2 + 1]; }
    else { px = yp[((k * TT + t - 1) * NN + n) * 2]; py = yp[((k * TT + t - 1) * NN + n) * 2 + 1]; }
    float vx = (lx - px) * HZf, vy = (ly - py) * HZf;
    int ui = 40 - (int)ly;
    int vi = 40 - (int)lx;
    ui = min(max(ui, 0), 79);
    vi = min(max(vi, 0), 79);
    int row = k * NN + n;
    u16* dst = lhalf_bf + ((size_t)t * 960 + row) * 48;
    if (lane < 32) {
        dst[lane] = f2bf(fmap[(lane * 80 + ui) * 80 + vi]);
    } else if (lane < 48) {
        int f = lane - 32;
        float a = vb[f] + vx * vw[f * 2 + 0] + vy * vw[f * 2 + 1];
        dst[lane] = f2bf(fmaxf(a, 0.0f));
    }
}

// ---------------- bins: compact 80B/row-step: u64 mask + u16 entries (w<<8|c) ----------------
__global__ __launch_bounds__(256) void bins4_k(const float* __restrict__ yp,
                                               u32* __restrict__ binc) {
    int tk = blockIdx.x;  // t*10 + k
    int k = tk % KK, t = tk / KK;
    int tid = threadIdx.x;
    __shared__ float xs[96], ys[96];
    __shared__ int win_s[96 * 36];
    __shared__ int cnt_s[96 * 36];
    if (tid < 96) {
        xs[tid] = yp[((k * TT + t) * NN + tid) * 2 + 0];
        ys[tid] = yp[((k * TT + t) * NN + tid) * 2 + 1];
    }
    for (int i = tid; i < 96 * 36; i += 256) { win_s[i] = -1; cnt_s[i] = 0; }
    __syncthreads();
    for (int p = tid; p < 96 * 96; p += 256) {
        int i = p / 96, j = p % 96;
        if (i == j) continue;
        float dx = xs[j] - xs[i], dy = ys[j] - ys[i];
        float dist = sqrtf(dx * dx + dy * dy);
        if (dist < R0f || dist > R1f) continue;
        float dsafe = fmaxf(dist, 1e-10f);
        float cost = fminf(fmaxf(dx / dsafe, -1.0f), 1.0f);
        float ac = acosf(cost);
        float theta = (dy < 0.0f) ? (TWO_PIf - ac) : ac;
        int ub = (int)((dist - R0f) / RSTEPf); ub = min(max(ub, 0), 5);
        int vb = (int)(theta / TSTEPf);        vb = min(max(vb, 0), 5);
        int b = ub * 6 + vb;
        atomicAdd(&cnt_s[i * 36 + b], 1);
        atomicMax(&win_s[i * 36 + b], j);
    }
    __syncthreads();
    if (tid < 96) {
        u32 base = (u32)(t * 960 + k * 96 + tid) * 20u;
        u16* entg = (u16*)(binc + base + 2);
        u64 mask = 0ull;
        int ne = 0;
        for (int b = 0; b < 36; ++b) {
            int w = win_s[tid * 36 + b];
            if (w >= 0) {
                mask |= 1ull << b;
                entg[ne++] = (u16)((w << 8) | cnt_s[tid * 36 + b]);
            }
        }
        binc[base] = (u32)mask;
        binc[base + 1] = (u32)(mask >> 32);
    }
}

// ---------------- init h0 slab ----------------
__global__ void init_h(const float* __restrict__ hx, float* __restrict__ h0hist) {
    int idx = blockIdx.x * blockDim.x + threadIdx.x;
    if (idx < 4608) h0hist[idx] = hx[idx];
}

// ---------------- persistent chain: 96 blocks x 1 wave, sense barrier ----------------
__global__ __launch_bounds__(64, 1) void chain_k(
    const float* __restrict__ hx, float* __restrict__ h0hist,
    const u16* __restrict__ lhalf_bf, const u32* __restrict__ binc,
    const u32* __restrict__ wscf_p, const u32* __restrict__ Wr_p,
    const u32* __restrict__ Wz_p, const u32* __restrict__ Win_p,
    const u32* __restrict__ Whn_p, const float* __restrict__ bias5,
    const float* __restrict__ scw, float* __restrict__ score_acc,
    float* __restrict__ hfin, int* flags) {
    const int r = blockIdx.x;      // 0..95
    const int lane = threadIdx.x;  // one wave
    const int lo = lane < 48 ? lane : 47;
    __shared__ u32 slh[960];       // 40 x 24 packed lhalf pairs (this row)
    __shared__ u32 sbin[800];      // 40 x 20 binc words (this row)
    __shared__ float shw[1728];    // winner rows (up to 36 x 48)
    __shared__ float shh[48], shrh[48];

    for (int i = lane; i < 960; i += 64) {
        int t = i / 24, dp = i - t * 24;
        slh[i] = *(const u32*)(lhalf_bf + ((size_t)t * 960 + r) * 48 + 2 * dp);
    }
    for (int i = lane; i < 800; i += 64)
        sbin[i] = binc[(size_t)((i / 20) * 960 + r) * 20 + (i % 20)];

    // gate weights -> registers (column lo); occupancy is irrelevant (96 blocks)
    u32 wr[72], wz[72], wiN[48], whn[24];
#pragma unroll
    for (int i = 0; i < 72; ++i) { wr[i] = Wr_p[i * 48 + lo]; wz[i] = Wz_p[i * 48 + lo]; }
#pragma unroll
    for (int i = 0; i < 48; ++i) wiN[i] = Win_p[i * 48 + lo];
#pragma unroll
    for (int i = 0; i < 24; ++i) whn[i] = Whn_p[i * 48 + lo];
    const float bR = bias5[lo], bZ = bias5[48 + lo], bI = bias5[96 + lo],
                bH = bias5[144 + lo], bS = bias5[192 + lo];
    const float swv = (lane < 48) ? scw[lane] : 0.f;
    float hreg = hx[r * 48 + lo];
    float score = 0.f;

    for (int t = 0; t < TT; ++t) {
        if (t > 0) {
            // wait: all 96 flags >= t (distributed, no RMW)
            for (;;) {
                int f0 = __hip_atomic_load(&flags[lane * 32], __ATOMIC_RELAXED,
                                           __HIP_MEMORY_SCOPE_AGENT);
                int f1 = (lane < 32)
                             ? __hip_atomic_load(&flags[(64 + lane) * 32], __ATOMIC_RELAXED,
                                                 __HIP_MEMORY_SCOPE_AGENT)
                             : t;
                if (__all((f0 >= t) && (f1 >= t))) break;
                __builtin_amdgcn_s_sleep(1);
            }
            __builtin_amdgcn_fence(__ATOMIC_ACQUIRE, "agent");
        }
        const float* hcur = h0hist + (size_t)t * 4608;
        u64 mask = ((u64)sbin[t * 20 + 1] << 32) | (u64)sbin[t * 20];
        int ne = __popcll(mask);
        const u16* ent = (const u16*)(sbin + t * 20 + 2);
        for (int i = lane; i < ne * 48; i += 64) {
            int e = i / 48, c = i - e * 48;
            shw[i] = hcur[((ent[e] >> 8) & 0xff) * 48 + c];
        }
        if (lane < 48) shh[lane] = hreg;
        // rhalf: predicated 9-unroll (uniform branches) + dynamic tail
        float acc = 0.f;
        u64 m2 = mask;
#pragma unroll
        for (int e = 0; e < 9; ++e) {
            if (e < ne) {
                int b = __ffsll((long long)m2) - 1;
                m2 &= m2 - 1;
                float cinv = 1.f / (float)(ent[e] & 0xff);
                const u32* wp = wscf_p + (b * 24) * 48 + lo;
                const float* xv = shw + e * 48;
                float a = 0.f;
#pragma unroll
                for (int dp = 0; dp < 24; ++dp) {
                    u32 u = wp[dp * 48];
                    a += bflo(u) * xv[2 * dp] + bfhi(u) * xv[2 * dp + 1];
                }
                acc += a * cinv;
            }
        }
        for (int e = 9; e < ne; ++e) {
            int b = __ffsll((long long)m2) - 1;
            m2 &= m2 - 1;
            float cinv = 1.f / (float)(ent[e] & 0xff);
            const u32* wp = wscf_p + (b * 24) * 48 + lo;
            const float* xv = shw + e * 48;
            float a = 0.f;
#pragma unroll
            for (int dp = 0; dp < 24; ++dp) {
                u32 u = wp[dp * 48];
                a += bflo(u) * xv[2 * dp] + bfhi(u) * xv[2 * dp + 1];
            }
            acc += a * cinv;
        }
        float rh = fmaxf(acc + bS, 0.f);
        if (lane < 48) shrh[lane] = rh;
        // gates (weights in registers, x via LDS broadcast)
        float aR = 0.f, aZ = 0.f, aI = 0.f, aH = 0.f;
#pragma unroll
        for (int dp = 0; dp < 24; ++dp) {
            u32 xp = slh[t * 24 + dp];
            float xlo = bflo(xp), xhi = bfhi(xp);
            aR += bflo(wr[dp]) * xlo + bfhi(wr[dp]) * xhi;
            aZ += bflo(wz[dp]) * xlo + bfhi(wz[dp]) * xhi;
            aI += bflo(wiN[dp]) * xlo + bfhi(wiN[dp]) * xhi;
        }
#pragma unroll
        for (int dp = 24; dp < 48; ++dp) {
            float xlo = shrh[2 * dp - 48], xhi = shrh[2 * dp - 47];
            aR += bflo(wr[dp]) * xlo + bfhi(wr[dp]) * xhi;
            aZ += bflo(wz[dp]) * xlo + bfhi(wz[dp]) * xhi;
            aI += bflo(wiN[dp]) * xlo + bfhi(wiN[dp]) * xhi;
        }
#pragma unroll
        for (int dp = 48; dp < 72; ++dp) {
            float xlo = shh[2 * dp - 96], xhi = shh[2 * dp - 95];
            aR += bflo(wr[dp]) * xlo + bfhi(wr[dp]) * xhi;
            aZ += bflo(wz[dp]) * xlo + bfhi(wz[dp]) * xhi;
            aH += bflo(whn[dp - 48]) * xlo + bfhi(whn[dp - 48]) * xhi;
        }
        float rr = sigmoidf_(aR + bR);
        float zz = sigmoidf_(aZ + bZ);
        float ng = tanhf(aI + bI + rr * (aH + bH));
        float hn = (1.f - zz) * ng + zz * hreg;
        hreg = hn;
        score += hn * swv;
        if (lane < 48) {
            h0hist[(size_t)(t + 1) * 4608 + r * 48 + lane] = hn;
            if (t == TT - 1) hfin[r * 48 + lane] = hn;
        }
        __builtin_amdgcn_fence(__ATOMIC_RELEASE, "agent");
        if (lane == 0)
            __hip_atomic_store(&flags[r * 32], t + 1, __ATOMIC_RELAXED,
                               __HIP_MEMORY_SCOPE_AGENT);
    }
    for (int off = 32; off; off >>= 1) score += __shfl_down(score, off);
    if (lane == 0) score_acc[r] = score;
}

// ---------------- rhalf for all follower row-steps (one parallel launch) ----------------
__global__ __launch_bounds__(256) void rhalf_k(
    const float* __restrict__ h0hist, const u32* __restrict__ binc,
    const u32* __restrict__ wscf_p, const float* __restrict__ bias5,
    u16* __restrict__ rhalf_all) {
    const int tid = threadIdx.x, wv = tid >> 6, lane = tid & 63;
    const int lo = lane < 48 ? lane : 47;
    int gid = blockIdx.x * 4 + wv;  // 0..34559
    int t = gid / 864, widx = gid - t * 864, row = 96 + widx;
    __shared__ float shw_all[4][1728];
    float* myw = shw_all[wv];
    const float* hcur = h0hist + (size_t)t * 4608;
    const u32* bp = binc + (size_t)(t * 960 + row) * 20;
    u64 mask = ((u64)bp[1] << 32) | (u64)bp[0];
    int ne = __popcll(mask);
    const u16* ent = (const u16*)(bp + 2);
    for (int i = lane; i < ne * 48; i += 64) {
        int e = i / 48, c = i - e * 48;
        myw[i] = hcur[((ent[e] >> 8) & 0xff) * 48 + c];
    }
    float acc = 0.f;
    u64 m2 = mask;
#pragma unroll
    for (int e = 0; e < 9; ++e) {
        if (e < ne) {
            int b = __ffsll((long long)m2) - 1;
            m2 &= m2 - 1;
            float cinv = 1.f / (float)(ent[e] & 0xff);
            const u32* wp = wscf_p + (b * 24) * 48 + lo;
            const float* xv = myw + e * 48;
            float a = 0.f;
#pragma unroll
            for (int dp = 0; dp < 24; ++dp) {
                u32 u = wp[dp * 48];
                a += bflo(u) * xv[2 * dp] + bfhi(u) * xv[2 * dp + 1];
            }
            acc += a * cinv;
        }
    }
    for (int e = 9; e < ne; ++e) {
        int b = __ffsll((long long)m2) - 1;
        m2 &= m2 - 1;
        float cinv = 1.f / (float)(ent[e] & 0xff);
        const u32* wp = wscf_p + (b * 24) * 48 + lo;
        const float* xv = myw + e * 48;
        float a = 0.f;
#pragma unroll
        for (int dp = 0; dp < 24; ++dp) {
            u32 u = wp[dp * 48];
            a += bflo(u) * xv[2 * dp] + bfhi(u) * xv[2 * dp + 1];
        }
        acc += a * cinv;
    }
    float rh = fmaxf(acc + bias5[192 + lo], 0.f);
    if (lane < 48) rhalf_all[((size_t)t * 864 + widx) * 48 + lane] = f2bf(rh);
}

// ---------------- followers: 4 rows/block, reg-cached Wr/Win/Whn, Wz in LDS ----------------
__global__ __launch_bounds__(256) void foll3_k(
    const float* __restrict__ hx, const u16* __restrict__ lhalf_bf,
    const u16* __restrict__ rhalf_all, const u32* __restrict__ Wr_p,
    const u32* __restrict__ Wz_p, const u32* __restrict__ Win_p,
    const u32* __restrict__ Whn_p, const float* __restrict__ bias5,
    const float* __restrict__ scw, float* __restrict__ score_acc,
    float* __restrict__ hfin) {
    const int tid = threadIdx.x, wv = tid >> 6, lane = tid & 63;
    const int lo = lane < 48 ? lane : 47;
    const int widx = blockIdx.x * 4 + wv;  // 0..863
    const int row = 96 + widx;
    __shared__ u32 sWz[3456];
    __shared__ u32 sx4[4][48];
    __shared__ float shh4[4][48];
    for (int i = tid; i < 3456; i += 256) sWz[i] = Wz_p[i];
    u32 wr[72], wiN[48], whn[24];
#pragma unroll
    for (int i = 0; i < 72; ++i) wr[i] = Wr_p[i * 48 + lo];
#pragma unroll
    for (int i = 0; i < 48; ++i) wiN[i] = Win_p[i * 48 + lo];
#pragma unroll
    for (int i = 0; i < 24; ++i) whn[i] = Whn_p[i * 48 + lo];
    u32* sx = sx4[wv];
    float* shh = shh4[wv];
    float hreg = hx[(row % 96) * 48 + lo];
    const float bR = bias5[lo], bZ = bias5[48 + lo], bI = bias5[96 + lo], bH = bias5[144 + lo];
    const float swv = (lane < 48) ? scw[lane] : 0.f;
    float score = 0.f;
    __syncthreads();
    // prefetch x(t=0)
    u32 pf = 0;
    if (lane < 24)
        pf = *(const u32*)(lhalf_bf + ((size_t)0 * 960 + row) * 48 + 2 * lane);
    else if (lane < 48)
        pf = *(const u32*)(rhalf_all + ((size_t)0 * 864 + widx) * 48 + 2 * (lane - 24));
    for (int t = 0; t < TT; ++t) {
        if (lane < 48) { sx[lane] = pf; shh[lane] = hreg; }
        if (t + 1 < TT) {
            if (lane < 24)
                pf = *(const u32*)(lhalf_bf + ((size_t)(t + 1) * 960 + row) * 48 + 2 * lane);
            else if (lane < 48)
                pf = *(const u32*)(rhalf_all + ((size_t)(t + 1) * 864 + widx) * 48 +
                                   2 * (lane - 24));
        }
        float aR = 0.f, aZ = 0.f, aI = 0.f, aH = 0.f;
#pragma unroll
        for (int dp = 0; dp < 48; ++dp) {
            u32 xp = sx[dp];
            float xlo = bflo(xp), xhi = bfhi(xp);
            u32 uZ = sWz[dp * 48 + lo];
            aR += bflo(wr[dp]) * xlo + bfhi(wr[dp]) * xhi;
            aZ += bflo(uZ) * xlo + bfhi(uZ) * xhi;
            aI += bflo(wiN[dp]) * xlo + bfhi(wiN[dp]) * xhi;
        }
#pragma unroll
        for (int dp = 48; dp < 72; ++dp) {
            float xlo = shh[2 * dp - 96], xhi = shh[2 * dp - 95];
            u32 uZ = sWz[dp * 48 + lo];
            aR += bflo(wr[dp]) * xlo + bfhi(wr[dp]) * xhi;
            aZ += bflo(uZ) * xlo + bfhi(uZ) * xhi;
            aH += bflo(whn[dp - 48]) * xlo + bfhi(whn[dp - 48]) * xhi;
        }
        float rr = sigmoidf_(aR + bR);
        float zz = sigmoidf_(aZ + bZ);
        float ng = tanhf(aI + bI + rr * (aH + bH));
        hreg = (1.f - zz) * ng + zz * hreg;
        score += hreg * swv;
    }
    if (lane < 48) hfin[(size_t)row * 48 + lane] = hreg;
    for (int off = 32; off; off >>= 1) score += __shfl_down(score, off);
    if (lane == 0) score_acc[row] = score;
}

// ---------------- epilogue ----------------
__global__ void final_k(const float* __restrict__ hlast, const float* __restrict__ score_acc,
                        const float* __restrict__ dyw, const float* __restrict__ dyb,
                        const float* __restrict__ scoreb, float* __restrict__ out) {
    int row = blockIdx.x, lane = threadIdx.x;
    int n = row % 96, k = row / 96;
    __shared__ float sh_h[48];
    if (lane < 48) sh_h[lane] = hlast[row * 48 + lane];
    __syncthreads();
    if (lane < 80) {
        float a = dyb[lane];
#pragma unroll 8
        for (int d = 0; d < 48; d++) a += sh_h[d] * dyw[lane * 48 + d];
        a = fmaxf(a, 0.0f);
        int j = lane / 40, tt = lane % 40;
        out[((k * TT + tt) * NN + n) * 2 + j] = a;
    } else if (lane == 80) {
        out[76800 + row] = score_acc[row] + 40.0f * scoreb[0];
    }
}

extern "C" void kernel_launch(void* const* d_in, const int* in_sizes, int n_in,
                              void* d_out, int out_size, void* d_ws, size_t ws_size,
                              hipStream_t stream) {
    const float* hx  = (const float*)d_in[0];
    const float* cur = (const float*)d_in[1];
    const float* yp  = (const float*)d_in[2];
    const float* img = (const float*)d_in[3];
    const float* c1w = (const float*)d_in[4];
    const float* c1b = (const float*)d_in[5];
    const float* c2w = (const float*)d_in[6];
    const float* c2b = (const float*)d_in[7];
    const float* vw  = (const float*)d_in[8];
    const float* vb  = (const float*)d_in[9];
    const float* wih = (const float*)d_in[10];
    const float* whh = (const float*)d_in[11];
    const float* bih = (const float*)d_in[12];
    const float* bhh = (const float*)d_in[13];
    const float* scfw = (const float*)d_in[14];
    const float* scfb = (const float*)d_in[15];
    const float* scw  = (const float*)d_in[16];
    const float* scb  = (const float*)d_in[17];
    const float* dyw  = (const float*)d_in[18];
    const float* dyb  = (const float*)d_in[19];
    float* out = (float*)d_out;

    char* ws = (char*)d_ws;
    // Layout (total 11,240,640 B). fmap1/fmap alias the front of binc: dead after
    // lhalf_k; bins4_k (writes binc) runs after lhalf_k.
    u32*   binc     = (u32*)(ws + 0);           // 3,072,000 -> 3072000
    float* fmap1    = (float*)(ws + 0);         //   409,600 (dead after conv2)
    float* fmap     = (float*)(ws + 409600);    //   819,200 (dead after lhalf_k)
    u16*   rhalf_all= (u16*)(ws + 3072000);     // 3,317,760 -> 6389760
    u16*   lhalf_bf = (u16*)(ws + 6389760);     // 3,686,400 -> 10076160
    float* h0hist   = (float*)(ws + 10076160);  //   755,712 -> 10831872
    float* hfin     = (float*)(ws + 10831872);  //   184,320 -> 11016192
    float* score_acc= (float*)(ws + 11016192);  //     3,840 -> 11020032
    u32*   wscf_p   = (u32*)(ws + 11020032);    //   165,888 -> 11185920
    u32*   Wr_p     = (u32*)(ws + 11185920);    //    13,824 -> 11199744
    u32*   Wz_p     = (u32*)(ws + 11199744);    //    13,824 -> 11213568
    u32*   Win_p    = (u32*)(ws + 11213568);    //     9,216 -> 11222784
    u32*   Whn_p    = (u32*)(ws + 11222784);    //     4,608 -> 11227392
    float* bias5    = (float*)(ws + 11227392);  //       960 -> 11228352
    int*   flags    = (int*)(ws + 11228352);    //    12,288 -> 11240640

    hipMemsetAsync(flags, 0, 12288, stream);

    conv1_k<<<400, 256, 0, stream>>>(img, c1w, c1b, fmap1);
    conv2_k<<<800, 256, 0, stream>>>(fmap1, c2w, c2b, fmap);
    prep_w3<<<204, 256, 0, stream>>>(scfw, wih, whh, bih, bhh, scfb, wscf_p, Wr_p, Wz_p,
                                     Win_p, Whn_p, bias5);
    lhalf_k<<<TT * KK * NN, 64, 0, stream>>>(yp, cur, fmap, vw, vb, lhalf_bf);
    bins4_k<<<TT * KK, 256, 0, stream>>>(yp, binc);
    init_h<<<18, 256, 0, stream>>>(hx, h0hist);

    chain_k<<<96, 64, 0, stream>>>(hx, h0hist, lhalf_bf, binc, wscf_p, Wr_p, Wz_p, Win_p,
                                   Whn_p, bias5, scw, score_acc, hfin, flags);
    rhalf_k<<<8640, 256, 0, stream>>>(h0hist, binc, wscf_p, bias5, rhalf_all);
    foll3_k<<<216, 256, 0, stream>>>(hx, lhalf_bf, rhalf_all, Wr_p, Wz_p, Win_p, Whn_p,
                                     bias5, scw, score_acc, hfin);
    final_k<<<960, 128, 0, stream>>>(hfin, score_acc, dyw, dyb, scb, out);
}

// Round 9
// 1382.754 us; speedup vs baseline: 1.2241x; 1.2241x over previous
//
#include <hip/hip_runtime.h>
#include <math.h>

#define KK 10
#define NN 96
#define TT 40

#define HZf 10.0f
#define R0f 0.5f
#define R1f 4.0f
#define RSTEPf ((4.0f - 0.5f) / 6.0f)
#define TWO_PIf 6.2831853071795864769f
#define TSTEPf (6.2831853071795864769f / 6.0f)

typedef unsigned short u16;
typedef unsigned int u32;
typedef unsigned long long u64;

__device__ __forceinline__ u16 f2bf(float f) {
    union { float f; unsigned u; } v; v.f = f;
    unsigned r = v.u + 0x7fffu + ((v.u >> 16) & 1u);
    return (u16)(r >> 16);
}
__device__ __forceinline__ float bflo(u32 u) {
    union { unsigned u; float f; } v; v.u = u << 16; return v.f;
}
__device__ __forceinline__ float bfhi(u32 u) {
    union { unsigned u; float f; } v; v.u = u & 0xffff0000u; return v.f;
}
__device__ __forceinline__ float bf2f(u16 h) {
    union { unsigned u; float f; } v; v.u = ((unsigned)h) << 16; return v.f;
}
__device__ __forceinline__ float sigmoidf_(float x) { return 1.0f / (1.0f + expf(-x)); }

// ---------------- conv1: (4,160,160) -> relu -> (16,80,80), s2 p2 ----------------
__global__ void conv1_k(const float* __restrict__ img, const float* __restrict__ w,
                        const float* __restrict__ b, float* __restrict__ out) {
    int idx = blockIdx.x * blockDim.x + threadIdx.x;
    if (idx >= 16 * 80 * 80) return;
    int x = idx % 80, y = (idx / 80) % 80, o = idx / 6400;
    float acc = b[o];
    for (int c = 0; c < 4; c++)
        for (int ky = 0; ky < 5; ky++) {
            int iy = y * 2 + ky - 2;
            if (iy < 0 || iy >= 160) continue;
            for (int kx = 0; kx < 5; kx++) {
                int ix = x * 2 + kx - 2;
                if (ix < 0 || ix >= 160) continue;
                acc += img[(c * 160 + iy) * 160 + ix] * w[((o * 4 + c) * 5 + ky) * 5 + kx];
            }
        }
    out[idx] = fmaxf(acc, 0.0f);
}

// ---------------- conv2: (16,80,80) -> relu -> (32,80,80), s1 p2 ----------------
__global__ void conv2_k(const float* __restrict__ in, const float* __restrict__ w,
                        const float* __restrict__ b, float* __restrict__ out) {
    int idx = blockIdx.x * blockDim.x + threadIdx.x;
    if (idx >= 32 * 80 * 80) return;
    int x = idx % 80, y = (idx / 80) % 80, o = idx / 6400;
    float acc = b[o];
    for (int c = 0; c < 16; c++)
        for (int ky = 0; ky < 5; ky++) {
            int iy = y + ky - 2;
            if (iy < 0 || iy >= 80) continue;
            for (int kx = 0; kx < 5; kx++) {
                int ix = x + kx - 2;
                if (ix < 0 || ix >= 80) continue;
                acc += in[(c * 80 + iy) * 80 + ix] * w[((o * 16 + c) * 5 + ky) * 5 + kx];
            }
        }
    out[idx] = fmaxf(acc, 0.0f);
}

// ---------------- weight prep: bf16 pair-packed planes ----------------
__global__ void prep_w3(const float* __restrict__ scf, const float* __restrict__ wih,
                        const float* __restrict__ whh, const float* __restrict__ bih,
                        const float* __restrict__ bhh, const float* __restrict__ scfb,
                        u32* __restrict__ wscf_p, u32* __restrict__ Wr_p,
                        u32* __restrict__ Wz_p, u32* __restrict__ Win_p,
                        u32* __restrict__ Whn_p, float* __restrict__ bias5) {
    int idx = blockIdx.x * blockDim.x + threadIdx.x;
    if (idx < 41472) {
        int o = idx % 48, dp = (idx / 48) % 24, b = idx / 1152;
        float v0 = scf[o * 1728 + b * 48 + 2 * dp];
        float v1 = scf[o * 1728 + b * 48 + 2 * dp + 1];
        wscf_p[idx] = (u32)f2bf(v0) | ((u32)f2bf(v1) << 16);
    } else if (idx < 44928) {
        int j = idx - 41472, od = j % 48, dp = j / 48;
        int kk0 = 2 * dp, kk1 = 2 * dp + 1;
        float v0 = kk0 < 96 ? wih[od * 96 + kk0] : whh[od * 48 + kk0 - 96];
        float v1 = kk1 < 96 ? wih[od * 96 + kk1] : whh[od * 48 + kk1 - 96];
        Wr_p[j] = (u32)f2bf(v0) | ((u32)f2bf(v1) << 16);
    } else if (idx < 48384) {
        int j = idx - 44928, od = j % 48, dp = j / 48;
        int row = 48 + od, kk0 = 2 * dp, kk1 = 2 * dp + 1;
        float v0 = kk0 < 96 ? wih[row * 96 + kk0] : whh[row * 48 + kk0 - 96];
        float v1 = kk1 < 96 ? wih[row * 96 + kk1] : whh[row * 48 + kk1 - 96];
        Wz_p[j] = (u32)f2bf(v0) | ((u32)f2bf(v1) << 16);
    } else if (idx < 50688) {
        int j = idx - 48384, od = j % 48, dp = j / 48;
        int row = 96 + od;
        Win_p[j] = (u32)f2bf(wih[row * 96 + 2 * dp]) | ((u32)f2bf(wih[row * 96 + 2 * dp + 1]) << 16);
    } else if (idx < 51840) {
        int j = idx - 50688, od = j % 48, dp = j / 48;
        int row = 96 + od;
        Whn_p[j] = (u32)f2bf(whh[row * 48 + 2 * dp]) | ((u32)f2bf(whh[row * 48 + 2 * dp + 1]) << 16);
    } else if (idx < 52080) {
        int j = idx - 51840, od = j % 48, q = j / 48;
        float v;
        if (q == 0) v = bih[od] + bhh[od];
        else if (q == 1) v = bih[48 + od] + bhh[48 + od];
        else if (q == 2) v = bih[96 + od];
        else if (q == 3) v = bhh[96 + od];
        else v = scfb[od];
        bias5[j] = v;
    }
}

// ---------------- lhalf (bf16) ----------------
__global__ void lhalf_k(const float* __restrict__ yp, const float* __restrict__ cur,
                        const float* __restrict__ fmap, const float* __restrict__ vw,
                        const float* __restrict__ vb, u16* __restrict__ lhalf_bf) {
    int item = blockIdx.x;  // t*960 + k*96 + n
    int n = item % NN, k = (item / NN) % KK, t = item / (KK * NN);
    int lane = threadIdx.x;
    float lx = yp[((k * TT + t) * NN + n) * 2 + 0];
    float ly = yp[((k * TT + t) * NN + n) * 2 + 1];
    float px, py;
    if (t == 0) { px = cur[n * 2]; py = cur[n * 2 + 1]; }
    else { px = yp[((k * TT + t - 1) * NN + n) * 2]; py = yp[((k * TT + t - 1) * NN + n) * 2 + 1]; }
    float vx = (lx - px) * HZf, vy = (ly - py) * HZf;
    int ui = 40 - (int)ly;
    int vi = 40 - (int)lx;
    ui = min(max(ui, 0), 79);
    vi = min(max(vi, 0), 79);
    int row = k * NN + n;
    u16* dst = lhalf_bf + ((size_t)t * 960 + row) * 48;
    if (lane < 32) {
        dst[lane] = f2bf(fmap[(lane * 80 + ui) * 80 + vi]);
    } else if (lane < 48) {
        int f = lane - 32;
        float a = vb[f] + vx * vw[f * 2 + 0] + vy * vw[f * 2 + 1];
        dst[lane] = f2bf(fmaxf(a, 0.0f));
    }
}

// ---------------- bins: compact 80B/row-step: u64 mask + u16 entries (w<<8|c) ----------------
__global__ __launch_bounds__(256) void bins4_k(const float* __restrict__ yp,
                                               u32* __restrict__ binc) {
    int tk = blockIdx.x;  // t*10 + k
    int k = tk % KK, t = tk / KK;
    int tid = threadIdx.x;
    __shared__ float xs[96], ys[96];
    __shared__ int win_s[96 * 36];
    __shared__ int cnt_s[96 * 36];
    if (tid < 96) {
        xs[tid] = yp[((k * TT + t) * NN + tid) * 2 + 0];
        ys[tid] = yp[((k * TT + t) * NN + tid) * 2 + 1];
    }
    for (int i = tid; i < 96 * 36; i += 256) { win_s[i] = -1; cnt_s[i] = 0; }
    __syncthreads();
    for (int p = tid; p < 96 * 96; p += 256) {
        int i = p / 96, j = p % 96;
        if (i == j) continue;
        float dx = xs[j] - xs[i], dy = ys[j] - ys[i];
        float dist = sqrtf(dx * dx + dy * dy);
        if (dist < R0f || dist > R1f) continue;
        float dsafe = fmaxf(dist, 1e-10f);
        float cost = fminf(fmaxf(dx / dsafe, -1.0f), 1.0f);
        float ac = acosf(cost);
        float theta = (dy < 0.0f) ? (TWO_PIf - ac) : ac;
        int ub = (int)((dist - R0f) / RSTEPf); ub = min(max(ub, 0), 5);
        int vb = (int)(theta / TSTEPf);        vb = min(max(vb, 0), 5);
        int b = ub * 6 + vb;
        atomicAdd(&cnt_s[i * 36 + b], 1);
        atomicMax(&win_s[i * 36 + b], j);
    }
    __syncthreads();
    if (tid < 96) {
        u32 base = (u32)(t * 960 + k * 96 + tid) * 20u;
        u16* entg = (u16*)(binc + base + 2);
        u64 mask = 0ull;
        int ne = 0;
        for (int b = 0; b < 36; ++b) {
            int w = win_s[tid * 36 + b];
            if (w >= 0) {
                mask |= 1ull << b;
                entg[ne++] = (u16)((w << 8) | cnt_s[tid * 36 + b]);
            }
        }
        binc[base] = (u32)mask;
        binc[base + 1] = (u32)(mask >> 32);
    }
}

// ---------------- init h0 slab ----------------
__global__ void init_h(const float* __restrict__ hx, float* __restrict__ h0hist) {
    int idx = blockIdx.x * blockDim.x + threadIdx.x;
    if (idx < 4608) h0hist[idx] = hx[idx];
}

// ---------------- persistent chain: fence-free sc-bypass exchange ----------------
// h values and flags move via RELAXED agent-scope atomics (sc0|sc1: bypass L1/L2,
// coherent at Infinity Cache). Ordering: s_waitcnt vmcnt(0) between h-stores and
// flag-store. NO fences -> L2 (weights, lhalf, bins) stays warm the whole kernel.
__global__ __launch_bounds__(64, 1) void chain_k(
    const float* __restrict__ hx, float* __restrict__ h0hist,
    const u16* __restrict__ lhalf_bf, const u32* __restrict__ binc,
    const u32* __restrict__ wscf_p, const u32* __restrict__ Wr_p,
    const u32* __restrict__ Wz_p, const u32* __restrict__ Win_p,
    const u32* __restrict__ Whn_p, const float* __restrict__ bias5,
    const float* __restrict__ scw, float* __restrict__ score_acc,
    float* __restrict__ hfin, int* flags) {
    const int r = blockIdx.x;      // 0..95
    const int lane = threadIdx.x;  // one wave
    const int lo = lane < 48 ? lane : 47;
    __shared__ u32 slh[960];       // 40 x 24 packed lhalf pairs (this row)
    __shared__ u32 sbin[800];      // 40 x 20 binc words (this row)
    __shared__ float shw[1728];    // winner rows (up to 36 x 48)
    __shared__ float shh[48], shrh[48];

    for (int i = lane; i < 960; i += 64) {
        int t = i / 24, dp = i - t * 24;
        slh[i] = *(const u32*)(lhalf_bf + ((size_t)t * 960 + r) * 48 + 2 * dp);
    }
    for (int i = lane; i < 800; i += 64)
        sbin[i] = binc[(size_t)((i / 20) * 960 + r) * 20 + (i % 20)];

    u32 wr[72], wz[72], wiN[48], whn[24];
#pragma unroll
    for (int i = 0; i < 72; ++i) { wr[i] = Wr_p[i * 48 + lo]; wz[i] = Wz_p[i * 48 + lo]; }
#pragma unroll
    for (int i = 0; i < 48; ++i) wiN[i] = Win_p[i * 48 + lo];
#pragma unroll
    for (int i = 0; i < 24; ++i) whn[i] = Whn_p[i * 48 + lo];
    const float bR = bias5[lo], bZ = bias5[48 + lo], bI = bias5[96 + lo],
                bH = bias5[144 + lo], bS = bias5[192 + lo];
    const float swv = (lane < 48) ? scw[lane] : 0.f;
    float hreg = hx[r * 48 + lo];
    float score = 0.f;

    for (int t = 0; t < TT; ++t) {
        if (t > 0) {
            for (;;) {
                int f0 = __hip_atomic_load(&flags[lane * 32], __ATOMIC_RELAXED,
                                           __HIP_MEMORY_SCOPE_AGENT);
                int f1 = (lane < 32)
                             ? __hip_atomic_load(&flags[(64 + lane) * 32], __ATOMIC_RELAXED,
                                                 __HIP_MEMORY_SCOPE_AGENT)
                             : t;
                if (__all((f0 >= t) && (f1 >= t))) break;
                __builtin_amdgcn_s_sleep(1);
            }
            // no fence: winner-h loads below are sc-bypass (coherent at IF$)
        }
        const float* hcur = h0hist + (size_t)t * 4608;
        u64 mask = ((u64)sbin[t * 20 + 1] << 32) | (u64)sbin[t * 20];
        int ne = __popcll(mask);
        const u16* ent = (const u16*)(sbin + t * 20 + 2);
        if (t == 0) {
            for (int i = lane; i < ne * 48; i += 64) {
                int e = i / 48, c = i - e * 48;
                shw[i] = hcur[((ent[e] >> 8) & 0xff) * 48 + c];
            }
        } else {
            for (int i = lane; i < ne * 48; i += 64) {
                int e = i / 48, c = i - e * 48;
                shw[i] = __hip_atomic_load(&hcur[((ent[e] >> 8) & 0xff) * 48 + c],
                                           __ATOMIC_RELAXED, __HIP_MEMORY_SCOPE_AGENT);
            }
        }
        if (lane < 48) shh[lane] = hreg;
        float acc = 0.f;
        u64 m2 = mask;
#pragma unroll
        for (int e = 0; e < 9; ++e) {
            if (e < ne) {
                int b = __ffsll((long long)m2) - 1;
                m2 &= m2 - 1;
                float cinv = 1.f / (float)(ent[e] & 0xff);
                const u32* wp = wscf_p + (b * 24) * 48 + lo;
                const float* xv = shw + e * 48;
                float a = 0.f;
#pragma unroll
                for (int dp = 0; dp < 24; ++dp) {
                    u32 u = wp[dp * 48];
                    a += bflo(u) * xv[2 * dp] + bfhi(u) * xv[2 * dp + 1];
                }
                acc += a * cinv;
            }
        }
        for (int e = 9; e < ne; ++e) {
            int b = __ffsll((long long)m2) - 1;
            m2 &= m2 - 1;
            float cinv = 1.f / (float)(ent[e] & 0xff);
            const u32* wp = wscf_p + (b * 24) * 48 + lo;
            const float* xv = shw + e * 48;
            float a = 0.f;
#pragma unroll
            for (int dp = 0; dp < 24; ++dp) {
                u32 u = wp[dp * 48];
                a += bflo(u) * xv[2 * dp] + bfhi(u) * xv[2 * dp + 1];
            }
            acc += a * cinv;
        }
        float rh = fmaxf(acc + bS, 0.f);
        if (lane < 48) shrh[lane] = rh;
        float aR = 0.f, aZ = 0.f, aI = 0.f, aH = 0.f;
#pragma unroll
        for (int dp = 0; dp < 24; ++dp) {
            u32 xp = slh[t * 24 + dp];
            float xlo = bflo(xp), xhi = bfhi(xp);
            aR += bflo(wr[dp]) * xlo + bfhi(wr[dp]) * xhi;
            aZ += bflo(wz[dp]) * xlo + bfhi(wz[dp]) * xhi;
            aI += bflo(wiN[dp]) * xlo + bfhi(wiN[dp]) * xhi;
        }
#pragma unroll
        for (int dp = 24; dp < 48; ++dp) {
            float xlo = shrh[2 * dp - 48], xhi = shrh[2 * dp - 47];
            aR += bflo(wr[dp]) * xlo + bfhi(wr[dp]) * xhi;
            aZ += bflo(wz[dp]) * xlo + bfhi(wz[dp]) * xhi;
            aI += bflo(wiN[dp]) * xlo + bfhi(wiN[dp]) * xhi;
        }
#pragma unroll
        for (int dp = 48; dp < 72; ++dp) {
            float xlo = shh[2 * dp - 96], xhi = shh[2 * dp - 95];
            aR += bflo(wr[dp]) * xlo + bfhi(wr[dp]) * xhi;
            aZ += bflo(wz[dp]) * xlo + bfhi(wz[dp]) * xhi;
            aH += bflo(whn[dp - 48]) * xlo + bfhi(whn[dp - 48]) * xhi;
        }
        float rr = sigmoidf_(aR + bR);
        float zz = sigmoidf_(aZ + bZ);
        float ng = tanhf(aI + bI + rr * (aH + bH));
        float hn = (1.f - zz) * ng + zz * hreg;
        hreg = hn;
        score += hn * swv;
        if (lane < 48)
            __hip_atomic_store(&h0hist[(size_t)(t + 1) * 4608 + r * 48 + lane], hn,
                               __ATOMIC_RELAXED, __HIP_MEMORY_SCOPE_AGENT);
        asm volatile("s_waitcnt vmcnt(0)" ::: "memory");
        if (lane == 0)
            __hip_atomic_store(&flags[r * 32], t + 1, __ATOMIC_RELAXED,
                               __HIP_MEMORY_SCOPE_AGENT);
    }
    if (lane < 48) hfin[r * 48 + lane] = hreg;
    for (int off = 32; off; off >>= 1) score += __shfl_down(score, off);
    if (lane == 0) score_acc[r] = score;
}

// ---------------- rhalf for all follower row-steps (one parallel launch) ----------------
__global__ __launch_bounds__(256) void rhalf_k(
    const float* __restrict__ h0hist, const u32* __restrict__ binc,
    const u32* __restrict__ wscf_p, const float* __restrict__ bias5,
    u16* __restrict__ rhalf_all) {
    const int tid = threadIdx.x, wv = tid >> 6, lane = tid & 63;
    const int lo = lane < 48 ? lane : 47;
    int gid = blockIdx.x * 4 + wv;  // 0..34559
    int t = gid / 864, widx = gid - t * 864, row = 96 + widx;
    __shared__ float shw_all[4][1728];
    float* myw = shw_all[wv];
    const float* hcur = h0hist + (size_t)t * 4608;
    const u32* bp = binc + (size_t)(t * 960 + row) * 20;
    u64 mask = ((u64)bp[1] << 32) | (u64)bp[0];
    int ne = __popcll(mask);
    const u16* ent = (const u16*)(bp + 2);
    for (int i = lane; i < ne * 48; i += 64) {
        int e = i / 48, c = i - e * 48;
        myw[i] = hcur[((ent[e] >> 8) & 0xff) * 48 + c];
    }
    float acc = 0.f;
    u64 m2 = mask;
#pragma unroll
    for (int e = 0; e < 9; ++e) {
        if (e < ne) {
            int b = __ffsll((long long)m2) - 1;
            m2 &= m2 - 1;
            float cinv = 1.f / (float)(ent[e] & 0xff);
            const u32* wp = wscf_p + (b * 24) * 48 + lo;
            const float* xv = myw + e * 48;
            float a = 0.f;
#pragma unroll
            for (int dp = 0; dp < 24; ++dp) {
                u32 u = wp[dp * 48];
                a += bflo(u) * xv[2 * dp] + bfhi(u) * xv[2 * dp + 1];
            }
            acc += a * cinv;
        }
    }
    for (int e = 9; e < ne; ++e) {
        int b = __ffsll((long long)m2) - 1;
        m2 &= m2 - 1;
        float cinv = 1.f / (float)(ent[e] & 0xff);
        const u32* wp = wscf_p + (b * 24) * 48 + lo;
        const float* xv = myw + e * 48;
        float a = 0.f;
#pragma unroll
        for (int dp = 0; dp < 24; ++dp) {
            u32 u = wp[dp * 48];
            a += bflo(u) * xv[2 * dp] + bfhi(u) * xv[2 * dp + 1];
        }
        acc += a * cinv;
    }
    float rh = fmaxf(acc + bias5[192 + lo], 0.f);
    if (lane < 48) rhalf_all[((size_t)t * 864 + widx) * 48 + lane] = f2bf(rh);
}

// ---------------- followers (round-7 measured structure): weights LDS, 1 wave/row ----------------
__global__ __launch_bounds__(64) void foll2_k(
    const float* __restrict__ hx, const u16* __restrict__ lhalf_bf,
    const u16* __restrict__ rhalf_all, const u32* __restrict__ Wr_p,
    const u32* __restrict__ Wz_p, const u32* __restrict__ Win_p,
    const u32* __restrict__ Whn_p, const float* __restrict__ bias5,
    const float* __restrict__ scw, float* __restrict__ score_acc,
    float* __restrict__ hfin) {
    const int widx = blockIdx.x;  // 0..863
    const int row = 96 + widx;
    const int lane = threadIdx.x;
    const int lo = lane < 48 ? lane : 47;
    __shared__ u32 sWr[3456], sWz[3456], sWin[2304];
    __shared__ u32 sx[48];
    __shared__ float shh[48];
    for (int i = lane; i < 3456; i += 64) { sWr[i] = Wr_p[i]; sWz[i] = Wz_p[i]; }
    for (int i = lane; i < 2304; i += 64) sWin[i] = Win_p[i];
    u32 whn[24];
#pragma unroll
    for (int dp = 0; dp < 24; ++dp) whn[dp] = Whn_p[dp * 48 + lo];
    float hreg = hx[(row % 96) * 48 + lo];
    const float bRb = bias5[lo], bZb = bias5[48 + lo], bIb = bias5[96 + lo],
                bHb = bias5[144 + lo];
    const float swv = (lane < 48) ? scw[lane] : 0.f;
    float score = 0.f;
    __syncthreads();
    for (int t = 0; t < TT; ++t) {
        if (lane < 24) {
            sx[lane] = *(const u32*)(lhalf_bf + ((size_t)t * 960 + row) * 48 + 2 * lane);
            sx[24 + lane] = *(const u32*)(rhalf_all + ((size_t)t * 864 + widx) * 48 + 2 * lane);
        }
        if (lane < 48) shh[lane] = hreg;
        __syncthreads();
        float aR = 0.f, aZ = 0.f, aI = 0.f, aH = 0.f;
#pragma unroll 8
        for (int dp = 0; dp < 48; ++dp) {
            u32 xp = sx[dp];
            float xlo = bflo(xp), xhi = bfhi(xp);
            u32 uR = sWr[dp * 48 + lo], uZ = sWz[dp * 48 + lo], uI = sWin[dp * 48 + lo];
            aR += bflo(uR) * xlo + bfhi(uR) * xhi;
            aZ += bflo(uZ) * xlo + bfhi(uZ) * xhi;
            aI += bflo(uI) * xlo + bfhi(uI) * xhi;
        }
#pragma unroll 8
        for (int dp = 48; dp < 72; ++dp) {
            float xlo = shh[2 * dp - 96], xhi = shh[2 * dp - 95];
            u32 uR = sWr[dp * 48 + lo], uZ = sWz[dp * 48 + lo], uH = whn[dp - 48];
            aR += bflo(uR) * xlo + bfhi(uR) * xhi;
            aZ += bflo(uZ) * xlo + bfhi(uZ) * xhi;
            aH += bflo(uH) * xlo + bfhi(uH) * xhi;
        }
        float rr = sigmoidf_(aR + bRb);
        float zz = sigmoidf_(aZ + bZb);
        float ng = tanhf(aI + bIb + rr * (aH + bHb));
        hreg = (1.0f - zz) * ng + zz * hreg;
        score += hreg * swv;
        __syncthreads();
    }
    if (lane < 48) hfin[(size_t)row * 48 + lane] = hreg;
    for (int off = 32; off; off >>= 1) score += __shfl_down(score, off);
    if (lane == 0) score_acc[row] = score;
}

// ---------------- epilogue ----------------
__global__ void final_k(const float* __restrict__ hlast, const float* __restrict__ score_acc,
                        const float* __restrict__ dyw, const float* __restrict__ dyb,
                        const float* __restrict__ scoreb, float* __restrict__ out) {
    int row = blockIdx.x, lane = threadIdx.x;
    int n = row % 96, k = row / 96;
    __shared__ float sh_h[48];
    if (lane < 48) sh_h[lane] = hlast[row * 48 + lane];
    __syncthreads();
    if (lane < 80) {
        float a = dyb[lane];
#pragma unroll 8
        for (int d = 0; d < 48; d++) a += sh_h[d] * dyw[lane * 48 + d];
        a = fmaxf(a, 0.0f);
        int j = lane / 40, tt = lane % 40;
        out[((k * TT + tt) * NN + n) * 2 + j] = a;
    } else if (lane == 80) {
        out[76800 + row] = score_acc[row] + 40.0f * scoreb[0];
    }
}

extern "C" void kernel_launch(void* const* d_in, const int* in_sizes, int n_in,
                              void* d_out, int out_size, void* d_ws, size_t ws_size,
                              hipStream_t stream) {
    const float* hx  = (const float*)d_in[0];
    const float* cur = (const float*)d_in[1];
    const float* yp  = (const float*)d_in[2];
    const float* img = (const float*)d_in[3];
    const float* c1w = (const float*)d_in[4];
    const float* c1b = (const float*)d_in[5];
    const float* c2w = (const float*)d_in[6];
    const float* c2b = (const float*)d_in[7];
    const float* vw  = (const float*)d_in[8];
    const float* vb  = (const float*)d_in[9];
    const float* wih = (const float*)d_in[10];
    const float* whh = (const float*)d_in[11];
    const float* bih = (const float*)d_in[12];
    const float* bhh = (const float*)d_in[13];
    const float* scfw = (const float*)d_in[14];
    const float* scfb = (const float*)d_in[15];
    const float* scw  = (const float*)d_in[16];
    const float* scb  = (const float*)d_in[17];
    const float* dyw  = (const float*)d_in[18];
    const float* dyb  = (const float*)d_in[19];
    float* out = (float*)d_out;

    char* ws = (char*)d_ws;
    u32*   binc     = (u32*)(ws + 0);           // 3,072,000 -> 3072000
    float* fmap1    = (float*)(ws + 0);         //   409,600 (dead after conv2)
    float* fmap     = (float*)(ws + 409600);    //   819,200 (dead after lhalf_k)
    u16*   rhalf_all= (u16*)(ws + 3072000);     // 3,317,760 -> 6389760
    u16*   lhalf_bf = (u16*)(ws + 6389760);     // 3,686,400 -> 10076160
    float* h0hist   = (float*)(ws + 10076160);  //   755,712 -> 10831872
    float* hfin     = (float*)(ws + 10831872);  //   184,320 -> 11016192
    float* score_acc= (float*)(ws + 11016192);  //     3,840 -> 11020032
    u32*   wscf_p   = (u32*)(ws + 11020032);    //   165,888 -> 11185920
    u32*   Wr_p     = (u32*)(ws + 11185920);    //    13,824 -> 11199744
    u32*   Wz_p     = (u32*)(ws + 11199744);    //    13,824 -> 11213568
    u32*   Win_p    = (u32*)(ws + 11213568);    //     9,216 -> 11222784
    u32*   Whn_p    = (u32*)(ws + 11222784);    //     4,608 -> 11227392
    float* bias5    = (float*)(ws + 11227392);  //       960 -> 11228352
    int*   flags    = (int*)(ws + 11228352);    //    12,288 -> 11240640

    hipMemsetAsync(flags, 0, 12288, stream);

    conv1_k<<<400, 256, 0, stream>>>(img, c1w, c1b, fmap1);
    conv2_k<<<800, 256, 0, stream>>>(fmap1, c2w, c2b, fmap);
    prep_w3<<<204, 256, 0, stream>>>(scfw, wih, whh, bih, bhh, scfb, wscf_p, Wr_p, Wz_p,
                                     Win_p, Whn_p, bias5);
    lhalf_k<<<TT * KK * NN, 64, 0, stream>>>(yp, cur, fmap, vw, vb, lhalf_bf);
    bins4_k<<<TT * KK, 256, 0, stream>>>(yp, binc);
    init_h<<<18, 256, 0, stream>>>(hx, h0hist);

    chain_k<<<96, 64, 0, stream>>>(hx, h0hist, lhalf_bf, binc, wscf_p, Wr_p, Wz_p, Win_p,
                                   Whn_p, bias5, scw, score_acc, hfin, flags);
    rhalf_k<<<8640, 256, 0, stream>>>(h0hist, binc, wscf_p, bias5, rhalf_all);
    foll2_k<<<864, 64, 0, stream>>>(hx, lhalf_bf, rhalf_all, Wr_p, Wz_p, Win_p, Whn_p,
                                    bias5, scw, score_acc, hfin);
    final_k<<<960, 128, 0, stream>>>(hfin, score_acc, dyw, dyb, scb, out);
}